// Round 1
// baseline (9244.653 us; speedup 1.0000x reference)
//
#include <hip/hip_runtime.h>
#include <math.h>

// ---------------------------------------------------------------------------
// Problem constants (B=1, TT=24, S=1024, C=1536, HID=1024, H=16, DH=64,
// KHID=128, FW=12, LOCAL=6, THETA=256, ROPE first 8 dims)
// ---------------------------------------------------------------------------

__device__ __forceinline__ float wsum(float v) {
  v += __shfl_xor(v, 32, 64);
  v += __shfl_xor(v, 16, 64);
  v += __shfl_xor(v, 8, 64);
  v += __shfl_xor(v, 4, 64);
  v += __shfl_xor(v, 2, 64);
  v += __shfl_xor(v, 1, 64);
  return v;
}
__device__ __forceinline__ float wmax(float v) {
  v = fmaxf(v, __shfl_xor(v, 32, 64));
  v = fmaxf(v, __shfl_xor(v, 16, 64));
  v = fmaxf(v, __shfl_xor(v, 8, 64));
  v = fmaxf(v, __shfl_xor(v, 4, 64));
  v = fmaxf(v, __shfl_xor(v, 2, 64));
  v = fmaxf(v, __shfl_xor(v, 1, 64));
  return v;
}

// RoPE: only first 8 dims rotate; pair p = lane>>1, inv = 256^(-p/4) = 4^-p.
__device__ __forceinline__ float rope_apply(float x, int lane, int t) {
  float pair = __shfl_xor(x, 1, 64);
  if (lane < 8) {
    int p = lane >> 1;
    float inv = exp2f(-2.0f * (float)p);
    float ang = (float)t * inv;
    float c = cosf(ang), s = sinf(ang);
    float rot = (lane & 1) ? pair : -pair;   // _rot: [-x1, x0, -x3, x2, ...]
    x = x * c + rot * s;
  }
  return x;
}

__device__ __forceinline__ float gelu_tanh(float x) {
  float x3 = x * x * x;
  return 0.5f * x * (1.0f + tanhf(0.7978845608028654f * (x + 0.044715f * x3)));
}

// ---------------------------------------------------------------------------
// Generic fp32 tiled GEMM.  C[M,N] = epi(A@B [+bias] [+add])
// amode: 0 = A[r*K+k]; 1 = concat(x in (s,t) row order, mouse window)
// emode: 0 none | 1 gelu(acc+bias) | 2 acc+bias | 3 add+perm(s,t->t,s) | 4 add
// ---------------------------------------------------------------------------
#define BM 64
#define BN 64
#define BK 16

__global__ __launch_bounds__(256) void gemm_f32(
    const float* __restrict__ A, const float* __restrict__ B,
    const float* __restrict__ bias, const float* __restrict__ add,
    float* __restrict__ C, int M, int N, int K, int amode, int emode,
    const float* __restrict__ xin, const float* __restrict__ mouse) {
  __shared__ float As[BM][BK];
  __shared__ float Bs[BK][BN];
  const int tid = threadIdx.x;
  const int bm = blockIdx.x * BM, bn = blockIdx.y * BN;
  const int tx = tid & 15, ty = tid >> 4;
  const int arow = tid >> 2, akc = (tid & 3) * 4;
  const int bkr = tid >> 4, bnc = (tid & 15) * 4;
  float acc[4][4] = {{0.f}};

  for (int k0 = 0; k0 < K; k0 += BK) {
    // ---- A tile (64 rows x 16 k), 4 consecutive k per thread ----
    float4 av;
    const int r = bm + arow;
    if (amode == 0) {
      if (k0 + BK <= K) {
        av = *reinterpret_cast<const float4*>(A + (size_t)r * K + k0 + akc);
      } else {
        float tmp[4];
#pragma unroll
        for (int e = 0; e < 4; e++) {
          int k = k0 + akc + e;
          tmp[e] = (k < K) ? A[(size_t)r * K + k] : 0.f;
        }
        av = make_float4(tmp[0], tmp[1], tmp[2], tmp[3]);
      }
    } else {
      // row r = s*24 + t ; cols [0,1536) = x[t*1024+s], [1536,1560) = mouse[8t+j]
      const int s = r / 24, t = r % 24;
      float tmp[4];
#pragma unroll
      for (int e = 0; e < 4; e++) {
        int k = k0 + akc + e;
        float vv = 0.f;
        if (k < 1536) vv = xin[(size_t)(t * 1024 + s) * 1536 + k];
        else if (k < 1560) vv = mouse[8 * t + (k - 1536)];
        tmp[e] = vv;
      }
      av = make_float4(tmp[0], tmp[1], tmp[2], tmp[3]);
    }
    *reinterpret_cast<float4*>(&As[arow][akc]) = av;

    // ---- B tile (16 k x 64 n), 4 consecutive n per thread ----
    const int kg = k0 + bkr;
    float4 bv = make_float4(0.f, 0.f, 0.f, 0.f);
    if (kg < K) bv = *reinterpret_cast<const float4*>(B + (size_t)kg * N + bn + bnc);
    *reinterpret_cast<float4*>(&Bs[bkr][bnc]) = bv;

    __syncthreads();
#pragma unroll
    for (int kk = 0; kk < BK; kk++) {
      float a[4];
#pragma unroll
      for (int i = 0; i < 4; i++) a[i] = As[ty * 4 + i][kk];
      const float4 b4 = *reinterpret_cast<const float4*>(&Bs[kk][tx * 4]);
      const float b[4] = {b4.x, b4.y, b4.z, b4.w};
#pragma unroll
      for (int i = 0; i < 4; i++)
#pragma unroll
        for (int j = 0; j < 4; j++) acc[i][j] = fmaf(a[i], b[j], acc[i][j]);
    }
    __syncthreads();
  }

  // ---- epilogue ----
#pragma unroll
  for (int i = 0; i < 4; i++) {
    const int r = bm + ty * 4 + i;
    if (r >= M) continue;
#pragma unroll
    for (int j = 0; j < 4; j++) {
      const int cc = bn + tx * 4 + j;
      if (cc >= N) continue;
      float v = acc[i][j];
      if (emode == 1) v = gelu_tanh(v + bias[cc]);
      else if (emode == 2) v = v + bias[cc];
      size_t orow = (size_t)r;
      if (emode == 3) { int s = r / 24, t = r % 24; orow = (size_t)(t * 1024 + s); }
      if (emode == 3 || emode == 4) v += add[orow * N + cc];
      C[orow * N + cc] = v;
    }
  }
}

// ---------------------------------------------------------------------------
// LayerNorm over last dim 1024, in place.  grid = rows, block = 256
// ---------------------------------------------------------------------------
__global__ __launch_bounds__(256) void ln_kernel(float* __restrict__ h,
                                                 const float* __restrict__ g,
                                                 const float* __restrict__ b) {
  const int r = blockIdx.x, tid = threadIdx.x;
  __shared__ float w1s[4], w2s[4];
  const size_t base = (size_t)r * 1024;
  float v[4];
  float s = 0.f;
#pragma unroll
  for (int i = 0; i < 4; i++) { v[i] = h[base + i * 256 + tid]; s += v[i]; }
  s = wsum(s);
  if ((tid & 63) == 0) w1s[tid >> 6] = s;
  __syncthreads();
  const float mean = (w1s[0] + w1s[1] + w1s[2] + w1s[3]) * (1.f / 1024.f);
  float sq = 0.f;
#pragma unroll
  for (int i = 0; i < 4; i++) { float d = v[i] - mean; sq += d * d; }
  sq = wsum(sq);
  if ((tid & 63) == 0) w2s[tid >> 6] = sq;
  __syncthreads();
  const float rstd =
      rsqrtf((w2s[0] + w2s[1] + w2s[2] + w2s[3]) * (1.f / 1024.f) + 1e-5f);
#pragma unroll
  for (int i = 0; i < 4; i++) {
    const int c = i * 256 + tid;
    h[base + c] = (v[i] - mean) * rstd * g[c] + b[c];
  }
}

// ---------------------------------------------------------------------------
// Mouse attention: one block per (local s, head).  qkv rows = ls*24+t (3072).
// RMS(q,k) + RoPE(t) + local-causal softmax(tt=24) + P@V.
// ---------------------------------------------------------------------------
__global__ __launch_bounds__(256) void attn_mouse(
    const float* __restrict__ qkv, const float* __restrict__ qn,
    const float* __restrict__ kn, float* __restrict__ o) {
  const int ls = blockIdx.x;
  const int h = blockIdx.y;
  __shared__ float qb[24][65], kb[24][65], vb[24][64];
  __shared__ float pb[4][24];
  const int tid = threadIdx.x, wave = tid >> 6, lane = tid & 63;

  for (int t = wave * 6; t < wave * 6 + 6; t++) {
    const float* base = qkv + (size_t)(ls * 24 + t) * 3072 + h * 64;
    const float qv = base[lane];
    const float kv = base[1024 + lane];
    const float vv = base[2048 + lane];
    const float q2 = wsum(qv * qv);
    const float k2 = wsum(kv * kv);
    float qs = qv * rsqrtf(q2 * (1.f / 64.f) + 1e-6f) * qn[lane];
    float ks = kv * rsqrtf(k2 * (1.f / 64.f) + 1e-6f) * kn[lane];
    qs = rope_apply(qs, lane, t);
    ks = rope_apply(ks, lane, t);
    qb[t][lane] = qs;
    kb[t][lane] = ks;
    vb[t][lane] = vv;
  }
  __syncthreads();

  for (int ii = 0; ii < 6; ii++) {
    const int i = wave * 6 + ii;
    const bool valid = (lane < 24) && (lane <= i) && (i - lane < 6);
    float sacc = 0.f;
    if (lane < 24) {
#pragma unroll 8
      for (int d = 0; d < 64; d++) sacc += qb[i][d] * kb[lane][d];
    }
    const float sv = valid ? sacc * 0.125f : -INFINITY;
    const float mx = wmax(sv);
    const float e = valid ? __expf(sv - mx) : 0.f;
    const float sum = wsum(e);
    if (lane < 24) pb[wave][lane] = e / sum;
    __syncthreads();
    float oacc = 0.f;
#pragma unroll
    for (int j = 0; j < 24; j++) oacc += pb[wave][j] * vb[j][lane];
    o[(size_t)(ls * 24 + i) * 1024 + h * 64 + lane] = oacc;
    __syncthreads();
  }
}

// ---------------------------------------------------------------------------
// Keyboard MLP: kc[104,128] = silu(keyb@w1+b1)@w2+b2.  1 block, 128 threads.
// ---------------------------------------------------------------------------
__global__ __launch_bounds__(128) void kb_mlp(
    const float* __restrict__ kb, const float* __restrict__ w1,
    const float* __restrict__ b1, const float* __restrict__ w2,
    const float* __restrict__ b2, float* __restrict__ kc) {
  __shared__ float t1[104][128];
  const int j = threadIdx.x;
  for (int r = 0; r < 104; r++) {
    float a = b1[j];
#pragma unroll
    for (int i = 0; i < 6; i++) a += kb[r * 6 + i] * w1[i * 128 + j];
    t1[r][j] = a / (1.f + __expf(-a));  // silu
  }
  __syncthreads();
  for (int r = 0; r < 104; r++) {
    float a = b2[j];
    for (int l = 0; l < 128; l++) a += t1[r][l] * w2[l * 128 + j];
    kc[r * 128 + j] = a;
  }
}

// ---------------------------------------------------------------------------
// K/V for keyboard attention: gk[t] = kc_flat[512t:512t+1536];
// kv = gk @ wkv (1536 x 2048); k = rope(rms(kv[:,0:1024])), v = kv[:,1024:2048]
// grid = 24 (t), block = 256
// ---------------------------------------------------------------------------
__global__ __launch_bounds__(256) void kv_key_kernel(
    const float* __restrict__ kc, const float* __restrict__ wkv,
    const float* __restrict__ knk, float* __restrict__ kkey,
    float* __restrict__ vkey) {
  const int t = blockIdx.x;
  __shared__ float g[1536];
  __shared__ float kvb[2048];
  const int tid = threadIdx.x;
  for (int i = tid; i < 1536; i += 256) g[i] = kc[512 * t + i];
  __syncthreads();
  for (int cc = 0; cc < 8; cc++) {
    const int col = cc * 256 + tid;
    float a = 0.f;
    for (int kk = 0; kk < 1536; kk++) a += g[kk] * wkv[(size_t)kk * 2048 + col];
    kvb[col] = a;
  }
  __syncthreads();
  const int wave = tid >> 6, lane = tid & 63;
  for (int hh = 0; hh < 4; hh++) {
    const int h = hh * 4 + wave;
    const float kv = kvb[h * 64 + lane];
    const float ss = wsum(kv * kv);
    float x = kv * rsqrtf(ss * (1.f / 64.f) + 1e-6f) * knk[lane];
    x = rope_apply(x, lane, t);
    kkey[(t * 16 + h) * 64 + lane] = x;
    vkey[(t * 16 + h) * 64 + lane] = kvb[1024 + h * 64 + lane];
  }
}

// ---------------------------------------------------------------------------
// q_key: in-place RMS(qn_key) + RoPE(t = r/1024).  grid = 24576 rows.
// ---------------------------------------------------------------------------
__global__ __launch_bounds__(256) void qkey_rmsrope(float* __restrict__ q,
                                                    const float* __restrict__ qn) {
  const int r = blockIdx.x;
  const int t = r >> 10;
  const int tid = threadIdx.x, wave = tid >> 6, lane = tid & 63;
  for (int hh = 0; hh < 4; hh++) {
    const int h = hh * 4 + wave;
    const size_t off = (size_t)r * 1024 + h * 64 + lane;
    const float v = q[off];
    const float ss = wsum(v * v);
    float x = v * rsqrtf(ss * (1.f / 64.f) + 1e-6f) * qn[lane];
    x = rope_apply(x, lane, t);
    q[off] = x;
  }
}

// ---------------------------------------------------------------------------
// Keyboard attention: one block per row r = t*1024+s; 16 heads, K len 24.
// ---------------------------------------------------------------------------
__global__ __launch_bounds__(256) void attn_key(
    const float* __restrict__ q, const float* __restrict__ kkey,
    const float* __restrict__ vkey, float* __restrict__ o) {
  const int r = blockIdx.x;
  const int t = r >> 10;
  const int tid = threadIdx.x, wave = tid >> 6, lane = tid & 63;
  const int u0 = (t >= 5) ? t - 5 : 0;
  for (int hh = 0; hh < 4; hh++) {
    const int h = hh * 4 + wave;
    const size_t qoff = (size_t)r * 1024 + h * 64 + lane;
    const float qd = q[qoff];
    float e_arr[24];
    float mx = -INFINITY;
    for (int u = u0; u <= t; u++) {
      const float partial = qd * kkey[(u * 16 + h) * 64 + lane];
      const float sv = wsum(partial) * 0.125f;
      e_arr[u] = sv;
      mx = fmaxf(mx, sv);
    }
    float sum = 0.f;
    for (int u = u0; u <= t; u++) {
      e_arr[u] = __expf(e_arr[u] - mx);
      sum += e_arr[u];
    }
    const float isum = 1.f / sum;
    float oacc = 0.f;
    for (int u = u0; u <= t; u++)
      oacc += e_arr[u] * vkey[(u * 16 + h) * 64 + lane];
    o[qoff] = oacc * isum;
  }
}

// ---------------------------------------------------------------------------
// Launch
// ---------------------------------------------------------------------------
extern "C" void kernel_launch(void* const* d_in, const int* in_sizes, int n_in,
                              void* d_out, int out_size, void* d_ws,
                              size_t ws_size, hipStream_t stream) {
  (void)in_sizes; (void)n_in; (void)out_size; (void)ws_size;
  const float* x      = (const float*)d_in[0];
  const float* mouse  = (const float*)d_in[1];
  const float* keyb   = (const float*)d_in[2];
  const float* kb_w1  = (const float*)d_in[6];
  const float* kb_b1  = (const float*)d_in[7];
  const float* kb_w2  = (const float*)d_in[8];
  const float* kb_b2  = (const float*)d_in[9];
  const float* mm_w1  = (const float*)d_in[10];
  const float* mm_b1  = (const float*)d_in[11];
  const float* mm_w2  = (const float*)d_in[12];
  const float* mm_b2  = (const float*)d_in[13];
  const float* ln_g   = (const float*)d_in[14];
  const float* ln_b   = (const float*)d_in[15];
  const float* qkv_w  = (const float*)d_in[16];
  const float* qn_img = (const float*)d_in[17];
  const float* kn_img = (const float*)d_in[18];
  const float* qn_key = (const float*)d_in[19];
  const float* kn_key = (const float*)d_in[20];
  const float* pm_w   = (const float*)d_in[21];
  const float* wq_key = (const float*)d_in[22];
  const float* wkv    = (const float*)d_in[23];
  const float* pk_w   = (const float*)d_in[24];

  float* ws   = (float*)d_ws;
  float* regA = ws;                       // 24576*1024 : T1 -> o_mouse -> o_key
  float* regB = regA + (size_t)24576 * 1024;  // 24576*1024 : H2 -> q_key
  float* regC = regB + (size_t)24576 * 1024;  // 6144*3072  : QKV chunk
  float* kc   = regC + (size_t)6144 * 3072;   // 104*128
  float* kkey = kc + 13312;               // 24*16*64
  float* vkey = kkey + 24576;             // 24*16*64
  float* outF = (float*)d_out;            // hidden lives here, then final out

  // keyboard branch K/V (tiny)
  kb_mlp<<<1, 128, 0, stream>>>(keyb, kb_w1, kb_b1, kb_w2, kb_b2, kc);
  kv_key_kernel<<<24, 256, 0, stream>>>(kc, wkv, kn_key, kkey, vkey);

  // G1: T1 = gelu(concat(x_perm, gm) @ mm_w1 + b1)   [concat fused into A-load]
  gemm_f32<<<dim3(384, 16), 256, 0, stream>>>(nullptr, mm_w1, mm_b1, nullptr,
                                              regA, 24576, 1024, 1560, 1, 1, x,
                                              mouse);
  // G2: H2 = T1 @ mm_w2 + b2 ; then LayerNorm in place
  gemm_f32<<<dim3(384, 16), 256, 0, stream>>>(regA, mm_w2, mm_b2, nullptr,
                                              regB, 24576, 1024, 1024, 0, 2,
                                              nullptr, nullptr);
  ln_kernel<<<24576, 256, 0, stream>>>(regB, ln_g, ln_b);

  // QKV + mouse attention, chunked 4x over s (6144 rows per chunk)
  for (int c = 0; c < 4; c++) {
    const float* h2c = regB + (size_t)c * 6144 * 1024;
    float* oc = regA + (size_t)c * 6144 * 1024;
    gemm_f32<<<dim3(96, 48), 256, 0, stream>>>(h2c, qkv_w, nullptr, nullptr,
                                               regC, 6144, 3072, 1024, 0, 0,
                                               nullptr, nullptr);
    attn_mouse<<<dim3(256, 16), 256, 0, stream>>>(regC, qn_img, kn_img, oc);
  }

  // G4: hidden = x + o_mouse @ pm_w   (row perm s,t -> t,s), hidden in d_out
  gemm_f32<<<dim3(384, 24), 256, 0, stream>>>(regA, pm_w, nullptr, x, outF,
                                              24576, 1536, 1024, 0, 3, nullptr,
                                              nullptr);
  // G5: q_key = hidden @ wq_key ; then RMS+RoPE in place
  gemm_f32<<<dim3(384, 16), 256, 0, stream>>>(outF, wq_key, nullptr, nullptr,
                                              regB, 24576, 1024, 1536, 0, 0,
                                              nullptr, nullptr);
  qkey_rmsrope<<<24576, 256, 0, stream>>>(regB, qn_key);

  // keyboard attention -> o_key (regA; o_mouse is dead)
  attn_key<<<24576, 256, 0, stream>>>(regB, kkey, vkey, regA);

  // G6: out = hidden + o_key @ pk_w  (element-wise in-place on d_out)
  gemm_f32<<<dim3(384, 24), 256, 0, stream>>>(regA, pk_w, nullptr, outF, outF,
                                              24576, 1536, 1024, 0, 4, nullptr,
                                              nullptr);
}

// Round 2
// 2587.442 us; speedup vs baseline: 3.5729x; 3.5729x over previous
//
#include <hip/hip_runtime.h>
#include <math.h>

// ---------------------------------------------------------------------------
// Constants: B=1, TT=24, S=1024, C=1536, HID=1024, H=16, DH=64, KHID=128,
// FW=12, LOCAL=6, THETA=256, ROPE dims (8,28,28)
// ---------------------------------------------------------------------------

typedef __attribute__((ext_vector_type(8))) __bf16 bf16x8;
typedef __attribute__((ext_vector_type(4))) float f32x4;

__device__ __forceinline__ unsigned short f2b(float f) {
  union { float f; unsigned u; } c; c.f = f;
  unsigned r = c.u + 0x7FFFu + ((c.u >> 16) & 1u);
  return (unsigned short)(r >> 16);
}
__device__ __forceinline__ float b2f(unsigned short h) {
  union { unsigned u; float f; } c; c.u = ((unsigned)h) << 16;
  return c.f;
}

__device__ __forceinline__ float wsum(float v) {
  v += __shfl_xor(v, 32, 64);
  v += __shfl_xor(v, 16, 64);
  v += __shfl_xor(v, 8, 64);
  v += __shfl_xor(v, 4, 64);
  v += __shfl_xor(v, 2, 64);
  v += __shfl_xor(v, 1, 64);
  return v;
}
__device__ __forceinline__ float wmax(float v) {
  v = fmaxf(v, __shfl_xor(v, 32, 64));
  v = fmaxf(v, __shfl_xor(v, 16, 64));
  v = fmaxf(v, __shfl_xor(v, 8, 64));
  v = fmaxf(v, __shfl_xor(v, 4, 64));
  v = fmaxf(v, __shfl_xor(v, 2, 64));
  v = fmaxf(v, __shfl_xor(v, 1, 64));
  return v;
}

// RoPE: only first 8 dims rotate; pair p = lane>>1, inv = 4^-p.
__device__ __forceinline__ float rope_apply(float x, int lane, int t) {
  float pair = __shfl_xor(x, 1, 64);
  if (lane < 8) {
    int p = lane >> 1;
    float inv = exp2f(-2.0f * (float)p);
    float ang = (float)t * inv;
    float c = cosf(ang), s = sinf(ang);
    float rot = (lane & 1) ? pair : -pair;
    x = x * c + rot * s;
  }
  return x;
}

__device__ __forceinline__ float gelu_tanh(float x) {
  float x3 = x * x * x;
  return 0.5f * x * (1.0f + tanhf(0.7978845608028654f * (x + 0.044715f * x3)));
}

__device__ __forceinline__ void gld_lds16(const void* g, void* l) {
  __builtin_amdgcn_global_load_lds(
      (const __attribute__((address_space(1))) void*)g,
      (__attribute__((address_space(3))) void*)l, 16, 0, 0);
}

// ---------------------------------------------------------------------------
// bf16 MFMA GEMM, 128x128 tile, BK=32, NT (Bt is [N,K] row-major bf16).
// M%128==0, N%128==0, K%32==0 required.
// EMODE: 0 gelu(acc+bias)->bf16 | 1 acc+bias->bf16 | 2 acc->f32
//        3 perm(s,t->t,s)+add(x)->f32 AND ->bf16 | 4 acc+addf->f32 (in place)
// ---------------------------------------------------------------------------
template <int EMODE>
__global__ __launch_bounds__(256) void gemm_bf16(
    const unsigned short* __restrict__ A, const unsigned short* __restrict__ Bt,
    const float* __restrict__ bias, const float* __restrict__ addf,
    float* __restrict__ outF, unsigned short* __restrict__ outB,
    int M, int N, int K) {
  __shared__ __align__(16) char smem[16384];
  const int tid = threadIdx.x;
  const int wave = tid >> 6, lane = tid & 63;
  const int bm = blockIdx.x * 128, bn = blockIdx.y * 128;
  const int m0 = (wave >> 1) * 64, n0 = (wave & 1) * 64;

  // staging: each wave issues 2 x 1KB loads for A and for B per K-iter
  const int lin0 = wave * 128 + lane;
  const int lin1 = lin0 + 64;
  const size_t rowbytes = (size_t)K * 2;
  const char* ag0 = (const char*)A + (size_t)(bm + (lin0 >> 2)) * rowbytes + (lin0 & 3) * 16;
  const char* ag1 = (const char*)A + (size_t)(bm + (lin1 >> 2)) * rowbytes + (lin1 & 3) * 16;
  const char* bg0 = (const char*)Bt + (size_t)(bn + (lin0 >> 2)) * rowbytes + (lin0 & 3) * 16;
  const char* bg1 = (const char*)Bt + (size_t)(bn + (lin1 >> 2)) * rowbytes + (lin1 & 3) * 16;
  char* As = smem;
  char* Bs = smem + 8192;
  char* lA0 = As + wave * 2048;
  char* lA1 = As + wave * 2048 + 1024;
  char* lB0 = Bs + wave * 2048;
  char* lB1 = Bs + wave * 2048 + 1024;

  const char* aBase = As + (m0 + (lane & 15)) * 64 + (lane >> 4) * 16;
  const char* bBase = Bs + (n0 + (lane & 15)) * 64 + (lane >> 4) * 16;

  f32x4 acc[4][4] = {};
  const int niter = K >> 5;
  size_t koff = 0;
  for (int it = 0; it < niter; ++it, koff += 64) {
    __syncthreads();
    gld_lds16(ag0 + koff, lA0);
    gld_lds16(ag1 + koff, lA1);
    gld_lds16(bg0 + koff, lB0);
    gld_lds16(bg1 + koff, lB1);
    __syncthreads();
    bf16x8 af[4], bfr[4];
#pragma unroll
    for (int i = 0; i < 4; i++) af[i] = *(const bf16x8*)(aBase + i * 1024);
#pragma unroll
    for (int j = 0; j < 4; j++) bfr[j] = *(const bf16x8*)(bBase + j * 1024);
#pragma unroll
    for (int i = 0; i < 4; i++)
#pragma unroll
      for (int j = 0; j < 4; j++)
        acc[i][j] = __builtin_amdgcn_mfma_f32_16x16x32_bf16(af[i], bfr[j],
                                                            acc[i][j], 0, 0, 0);
  }

  // epilogue: C/D map col = lane&15, row = (lane>>4)*4 + reg
#pragma unroll
  for (int i = 0; i < 4; i++) {
    const int rbase = bm + m0 + i * 16 + (lane >> 4) * 4;
#pragma unroll
    for (int j = 0; j < 4; j++) {
      const int n = bn + n0 + j * 16 + (lane & 15);
#pragma unroll
      for (int rr = 0; rr < 4; rr++) {
        const int r = rbase + rr;
        float v = acc[i][j][rr];
        if (EMODE == 0) {
          v = gelu_tanh(v + bias[n]);
          outB[(size_t)r * N + n] = f2b(v);
        } else if (EMODE == 1) {
          v += bias[n];
          outB[(size_t)r * N + n] = f2b(v);
        } else if (EMODE == 2) {
          outF[(size_t)r * N + n] = v;
        } else if (EMODE == 3) {
          const int s = r / 24, t = r - s * 24;
          const size_t orow = (size_t)t * 1024 + s;
          v += addf[orow * N + n];
          outF[orow * N + n] = v;
          outB[orow * N + n] = f2b(v);
        } else {
          const size_t off = (size_t)r * N + n;
          v += addf[off];
          outF[off] = v;
        }
      }
    }
  }
}

// ---------------------------------------------------------------------------
// Weight convert+transpose: in fp32 [K,N] -> out bf16 [N,K2], zero-pad k>=K.
// grid (K2/32, N/32), block 256.
// ---------------------------------------------------------------------------
__global__ __launch_bounds__(256) void conv_transpose(
    const float* __restrict__ in, unsigned short* __restrict__ out, int K,
    int N, int K2) {
  __shared__ float tile[32][33];
  const int k0 = blockIdx.x * 32, n0 = blockIdx.y * 32;
  const int tn = threadIdx.x & 31, tk = threadIdx.x >> 5;
#pragma unroll
  for (int kk = tk; kk < 32; kk += 8) {
    const int k = k0 + kk;
    tile[kk][tn] = (k < K) ? in[(size_t)k * N + n0 + tn] : 0.f;
  }
  __syncthreads();
#pragma unroll
  for (int nn = tk; nn < 32; nn += 8) {
    out[(size_t)(n0 + nn) * K2 + k0 + tn] = f2b(tile[tn][nn]);
  }
}

// ---------------------------------------------------------------------------
// A1[r=s*24+t][k] = bf16( k<1536 ? x[(t*1024+s)*1536+k]
//                        : k<1560 ? mouse[8t+k-1536] : 0 ),  K2=1568
// ---------------------------------------------------------------------------
__global__ __launch_bounds__(256) void build_a1(const float* __restrict__ x,
                                                const float* __restrict__ mouse,
                                                unsigned short* __restrict__ A1) {
  const int r = blockIdx.x;
  const int s = r / 24, t = r - s * 24;
  const float* xrow = x + (size_t)(t * 1024 + s) * 1536;
  unsigned short* arow = A1 + (size_t)r * 1568;
  for (int k = threadIdx.x; k < 1568; k += 256) {
    float v = 0.f;
    if (k < 1536) v = xrow[k];
    else if (k < 1560) v = mouse[8 * t + (k - 1536)];
    arow[k] = f2b(v);
  }
}

// ---------------------------------------------------------------------------
// LayerNorm over last dim 1024, bf16 in place. grid = rows, block = 256
// ---------------------------------------------------------------------------
__global__ __launch_bounds__(256) void ln_bf16(unsigned short* __restrict__ h,
                                               const float* __restrict__ g,
                                               const float* __restrict__ b) {
  const int r = blockIdx.x, tid = threadIdx.x;
  __shared__ float w1s[4], w2s[4];
  const size_t base = (size_t)r * 1024;
  float v[4];
  float s = 0.f;
#pragma unroll
  for (int i = 0; i < 4; i++) { v[i] = b2f(h[base + i * 256 + tid]); s += v[i]; }
  s = wsum(s);
  if ((tid & 63) == 0) w1s[tid >> 6] = s;
  __syncthreads();
  const float mean = (w1s[0] + w1s[1] + w1s[2] + w1s[3]) * (1.f / 1024.f);
  float sq = 0.f;
#pragma unroll
  for (int i = 0; i < 4; i++) { float d = v[i] - mean; sq += d * d; }
  sq = wsum(sq);
  if ((tid & 63) == 0) w2s[tid >> 6] = sq;
  __syncthreads();
  const float rstd =
      rsqrtf((w2s[0] + w2s[1] + w2s[2] + w2s[3]) * (1.f / 1024.f) + 1e-5f);
#pragma unroll
  for (int i = 0; i < 4; i++) {
    const int c = i * 256 + tid;
    h[base + c] = f2b((v[i] - mean) * rstd * g[c] + b[c]);
  }
}

// ---------------------------------------------------------------------------
// Mouse attention: block per (local s, head). qkv rows = ls*24+t, fp32.
// Writes o (bf16).
// ---------------------------------------------------------------------------
__global__ __launch_bounds__(256) void attn_mouse(
    const float* __restrict__ qkv, const float* __restrict__ qn,
    const float* __restrict__ kn, unsigned short* __restrict__ o) {
  const int ls = blockIdx.x;
  const int h = blockIdx.y;
  __shared__ float qb[24][65], kb[24][65], vb[24][64];
  __shared__ float pb[4][24];
  const int tid = threadIdx.x, wave = tid >> 6, lane = tid & 63;

  for (int t = wave * 6; t < wave * 6 + 6; t++) {
    const float* base = qkv + (size_t)(ls * 24 + t) * 3072 + h * 64;
    const float qv = base[lane];
    const float kv = base[1024 + lane];
    const float vv = base[2048 + lane];
    const float q2 = wsum(qv * qv);
    const float k2 = wsum(kv * kv);
    float qs = qv * rsqrtf(q2 * (1.f / 64.f) + 1e-6f) * qn[lane];
    float ks = kv * rsqrtf(k2 * (1.f / 64.f) + 1e-6f) * kn[lane];
    qs = rope_apply(qs, lane, t);
    ks = rope_apply(ks, lane, t);
    qb[t][lane] = qs;
    kb[t][lane] = ks;
    vb[t][lane] = vv;
  }
  __syncthreads();

  for (int ii = 0; ii < 6; ii++) {
    const int i = wave * 6 + ii;
    const bool valid = (lane < 24) && (lane <= i) && (i - lane < 6);
    float sacc = 0.f;
    if (lane < 24) {
#pragma unroll 8
      for (int d = 0; d < 64; d++) sacc += qb[i][d] * kb[lane][d];
    }
    const float sv = valid ? sacc * 0.125f : -INFINITY;
    const float mx = wmax(sv);
    const float e = valid ? __expf(sv - mx) : 0.f;
    const float sum = wsum(e);
    if (lane < 24) pb[wave][lane] = e / sum;
    __syncthreads();
    float oacc = 0.f;
#pragma unroll
    for (int j = 0; j < 24; j++) oacc += pb[wave][j] * vb[j][lane];
    o[(size_t)(ls * 24 + i) * 1024 + h * 64 + lane] = f2b(oacc);
    __syncthreads();
  }
}

// ---------------------------------------------------------------------------
// Keyboard MLP: kc[104,128] = silu(keyb@w1+b1)@w2+b2.
// ---------------------------------------------------------------------------
__global__ __launch_bounds__(128) void kb_mlp(
    const float* __restrict__ kb, const float* __restrict__ w1,
    const float* __restrict__ b1, const float* __restrict__ w2,
    const float* __restrict__ b2, float* __restrict__ kc) {
  __shared__ float t1[104][128];
  const int j = threadIdx.x;
  for (int r = 0; r < 104; r++) {
    float a = b1[j];
#pragma unroll
    for (int i = 0; i < 6; i++) a += kb[r * 6 + i] * w1[i * 128 + j];
    t1[r][j] = a / (1.f + __expf(-a));
  }
  __syncthreads();
  for (int r = 0; r < 104; r++) {
    float a = b2[j];
    for (int l = 0; l < 128; l++) a += t1[r][l] * w2[l * 128 + j];
    kc[r * 128 + j] = a;
  }
}

// ---------------------------------------------------------------------------
// K/V for keyboard attention (fp32, tiny).
// ---------------------------------------------------------------------------
__global__ __launch_bounds__(256) void kv_key_kernel(
    const float* __restrict__ kc, const float* __restrict__ wkv,
    const float* __restrict__ knk, float* __restrict__ kkey,
    float* __restrict__ vkey) {
  const int t = blockIdx.x;
  __shared__ float g[1536];
  __shared__ float kvb[2048];
  const int tid = threadIdx.x;
  for (int i = tid; i < 1536; i += 256) g[i] = kc[512 * t + i];
  __syncthreads();
  for (int cc = 0; cc < 8; cc++) {
    const int col = cc * 256 + tid;
    float a = 0.f;
    for (int kk = 0; kk < 1536; kk++) a += g[kk] * wkv[(size_t)kk * 2048 + col];
    kvb[col] = a;
  }
  __syncthreads();
  const int wave = tid >> 6, lane = tid & 63;
  for (int hh = 0; hh < 4; hh++) {
    const int h = hh * 4 + wave;
    const float kv = kvb[h * 64 + lane];
    const float ss = wsum(kv * kv);
    float x = kv * rsqrtf(ss * (1.f / 64.f) + 1e-6f) * knk[lane];
    x = rope_apply(x, lane, t);
    kkey[(t * 16 + h) * 64 + lane] = x;
    vkey[(t * 16 + h) * 64 + lane] = kvb[1024 + h * 64 + lane];
  }
}

// ---------------------------------------------------------------------------
// q_key: in-place RMS(qn_key) + RoPE(t = r/1024), fp32. grid = 24576 rows.
// ---------------------------------------------------------------------------
__global__ __launch_bounds__(256) void qkey_rmsrope(float* __restrict__ q,
                                                    const float* __restrict__ qn) {
  const int r = blockIdx.x;
  const int t = r >> 10;
  const int tid = threadIdx.x, wave = tid >> 6, lane = tid & 63;
  for (int hh = 0; hh < 4; hh++) {
    const int h = hh * 4 + wave;
    const size_t off = (size_t)r * 1024 + h * 64 + lane;
    const float v = q[off];
    const float ss = wsum(v * v);
    float x = v * rsqrtf(ss * (1.f / 64.f) + 1e-6f) * qn[lane];
    x = rope_apply(x, lane, t);
    q[off] = x;
  }
}

// ---------------------------------------------------------------------------
// Keyboard attention: block per row r = t*1024+s; writes bf16.
// ---------------------------------------------------------------------------
__global__ __launch_bounds__(256) void attn_key(
    const float* __restrict__ q, const float* __restrict__ kkey,
    const float* __restrict__ vkey, unsigned short* __restrict__ o) {
  const int r = blockIdx.x;
  const int t = r >> 10;
  const int tid = threadIdx.x, wave = tid >> 6, lane = tid & 63;
  const int u0 = (t >= 5) ? t - 5 : 0;
  for (int hh = 0; hh < 4; hh++) {
    const int h = hh * 4 + wave;
    const size_t qoff = (size_t)r * 1024 + h * 64 + lane;
    const float qd = q[qoff];
    float e_arr[24];
    float mx = -INFINITY;
    for (int u = u0; u <= t; u++) {
      const float partial = qd * kkey[(u * 16 + h) * 64 + lane];
      const float sv = wsum(partial) * 0.125f;
      e_arr[u] = sv;
      mx = fmaxf(mx, sv);
    }
    float sum = 0.f;
    for (int u = u0; u <= t; u++) {
      e_arr[u] = __expf(e_arr[u] - mx);
      sum += e_arr[u];
    }
    const float isum = 1.f / sum;
    float oacc = 0.f;
    for (int u = u0; u <= t; u++)
      oacc += e_arr[u] * vkey[(u * 16 + h) * 64 + lane];
    o[qoff] = f2b(oacc * isum);
  }
}

// ---------------------------------------------------------------------------
// Launch
// ---------------------------------------------------------------------------
extern "C" void kernel_launch(void* const* d_in, const int* in_sizes, int n_in,
                              void* d_out, int out_size, void* d_ws,
                              size_t ws_size, hipStream_t stream) {
  (void)in_sizes; (void)n_in; (void)out_size; (void)ws_size;
  const float* x      = (const float*)d_in[0];
  const float* mouse  = (const float*)d_in[1];
  const float* keyb   = (const float*)d_in[2];
  const float* kb_w1  = (const float*)d_in[6];
  const float* kb_b1  = (const float*)d_in[7];
  const float* kb_w2  = (const float*)d_in[8];
  const float* kb_b2  = (const float*)d_in[9];
  const float* mm_w1  = (const float*)d_in[10];
  const float* mm_b1  = (const float*)d_in[11];
  const float* mm_w2  = (const float*)d_in[12];
  const float* mm_b2  = (const float*)d_in[13];
  const float* ln_g   = (const float*)d_in[14];
  const float* ln_b   = (const float*)d_in[15];
  const float* qkv_w  = (const float*)d_in[16];
  const float* qn_img = (const float*)d_in[17];
  const float* kn_img = (const float*)d_in[18];
  const float* qn_key = (const float*)d_in[19];
  const float* kn_key = (const float*)d_in[20];
  const float* pm_w   = (const float*)d_in[21];
  const float* wq_key = (const float*)d_in[22];
  const float* wkv    = (const float*)d_in[23];
  const float* pk_w   = (const float*)d_in[24];

  // ---- workspace layout (bytes, 256-aligned) ----
  char* ws = (char*)d_ws;
  size_t off = 0;
  auto alloc = [&](size_t bytes) {
    char* p = ws + off;
    off += (bytes + 255) & ~(size_t)255;
    return p;
  };
  unsigned short* w1t  = (unsigned short*)alloc((size_t)1024 * 1568 * 2);
  unsigned short* w2t  = (unsigned short*)alloc((size_t)1024 * 1024 * 2);
  unsigned short* qkvt = (unsigned short*)alloc((size_t)3072 * 1024 * 2);
  unsigned short* pmt  = (unsigned short*)alloc((size_t)1536 * 1024 * 2);
  unsigned short* wqt  = (unsigned short*)alloc((size_t)1024 * 1536 * 2);
  unsigned short* pkt  = (unsigned short*)alloc((size_t)1536 * 1024 * 2);
  float* kc   = (float*)alloc(104 * 128 * 4);
  float* kkey = (float*)alloc(24 * 16 * 64 * 4);
  float* vkey = (float*)alloc(24 * 16 * 64 * 4);
  char* reg1 = alloc((size_t)24576 * 1024 * 4);  // A1 bf16 -> QKV chunk f32 -> qkey f32
  char* reg2 = alloc((size_t)24576 * 1024 * 2);  // T1 bf16 -> o_mouse bf16 -> o_key bf16
  char* reg3 = alloc((size_t)24576 * 1536 * 2);  // H2 bf16 -> hiddenB bf16

  unsigned short* A1    = (unsigned short*)reg1;
  float* qkvc           = (float*)reg1;   // QKV chunk (75.5MB <= 100.7MB)
  float* qkey           = (float*)reg1;
  unsigned short* T1    = (unsigned short*)reg2;
  unsigned short* omou  = (unsigned short*)reg2;
  unsigned short* okey  = (unsigned short*)reg2;
  unsigned short* H2    = (unsigned short*)reg3;
  unsigned short* hidB  = (unsigned short*)reg3;
  float* outF = (float*)d_out;

  // ---- weight conversion (transposed bf16) ----
  conv_transpose<<<dim3(49, 32), 256, 0, stream>>>(mm_w1, w1t, 1560, 1024, 1568);
  conv_transpose<<<dim3(32, 32), 256, 0, stream>>>(mm_w2, w2t, 1024, 1024, 1024);
  conv_transpose<<<dim3(32, 96), 256, 0, stream>>>(qkv_w, qkvt, 1024, 3072, 1024);
  conv_transpose<<<dim3(32, 48), 256, 0, stream>>>(pm_w, pmt, 1024, 1536, 1024);
  conv_transpose<<<dim3(48, 32), 256, 0, stream>>>(wq_key, wqt, 1536, 1024, 1536);
  conv_transpose<<<dim3(32, 48), 256, 0, stream>>>(pk_w, pkt, 1024, 1536, 1024);

  // keyboard branch K/V (tiny, fp32)
  kb_mlp<<<1, 128, 0, stream>>>(keyb, kb_w1, kb_b1, kb_w2, kb_b2, kc);
  kv_key_kernel<<<24, 256, 0, stream>>>(kc, wkv, kn_key, kkey, vkey);

  // A1 = bf16(concat(x perm, gm))
  build_a1<<<24576, 256, 0, stream>>>(x, mouse, A1);

  // G1: T1 = gelu(A1 @ W1 + b1) -> bf16
  gemm_bf16<0><<<dim3(192, 8), 256, 0, stream>>>(A1, w1t, mm_b1, nullptr,
                                                 nullptr, T1, 24576, 1024, 1568);
  // G2: H2 = T1 @ W2 + b2 -> bf16 ; LayerNorm in place
  gemm_bf16<1><<<dim3(192, 8), 256, 0, stream>>>(T1, w2t, mm_b2, nullptr,
                                                 nullptr, H2, 24576, 1024, 1024);
  ln_bf16<<<24576, 256, 0, stream>>>(H2, ln_g, ln_b);

  // QKV + mouse attention, chunked 4x over s (6144 rows per chunk)
  for (int c = 0; c < 4; c++) {
    const unsigned short* h2c = H2 + (size_t)c * 6144 * 1024;
    unsigned short* oc = omou + (size_t)c * 6144 * 1024;
    gemm_bf16<2><<<dim3(48, 24), 256, 0, stream>>>(h2c, qkvt, nullptr, nullptr,
                                                   qkvc, nullptr, 6144, 3072,
                                                   1024);
    attn_mouse<<<dim3(256, 16), 256, 0, stream>>>(qkvc, qn_img, kn_img, oc);
  }

  // G4: hidden = x + o_mouse @ pm_w  (perm s,t -> t,s); f32 to d_out + bf16
  gemm_bf16<3><<<dim3(192, 12), 256, 0, stream>>>(omou, pmt, nullptr, x, outF,
                                                  hidB, 24576, 1536, 1024);
  // G5: q_key = hiddenB @ wq_key -> f32 ; RMS+RoPE in place
  gemm_bf16<2><<<dim3(192, 8), 256, 0, stream>>>(hidB, wqt, nullptr, nullptr,
                                                 qkey, nullptr, 24576, 1024,
                                                 1536);
  qkey_rmsrope<<<24576, 256, 0, stream>>>(qkey, qn_key);

  // keyboard attention -> o_key bf16
  attn_key<<<24576, 256, 0, stream>>>(qkey, kkey, vkey, okey);

  // G6: out = hidden + o_key @ pk_w (in place on d_out)
  gemm_bf16<4><<<dim3(192, 12), 256, 0, stream>>>(okey, pkt, nullptr, outF,
                                                  outF, nullptr, 24576, 1536,
                                                  1024);
}